// Round 1
// baseline (115.079 us; speedup 1.0000x reference)
//
#include <hip/hip_runtime.h>
#include <math.h>

#define NNODES   8192
#define NODE_NUM 256
#define MAX_DEG  16
#define N_FEAT   128
#define N_HID    256
#define N_CLASS  64

// ---------------------------------------------------------------------------
// K1: agg_x = adj @ x   (binary adjacency: dedupe neighbor ids, skip -1)
// 2 nodes per block of 256 threads; 128 threads per node (one per feature).
// ---------------------------------------------------------------------------
__global__ __launch_bounds__(256) void k_agg_x(const float* __restrict__ x,
                                               const int* __restrict__ edge,
                                               float* __restrict__ agg) {
    const int node = blockIdx.x * 2 + (threadIdx.x >> 7);
    const int f    = threadIdx.x & 127;
    const int base = node & ~(NODE_NUM - 1);
    const int* e = edge + node * MAX_DEG;
    int ids[MAX_DEG];
#pragma unroll
    for (int k = 0; k < MAX_DEG; ++k) ids[k] = e[k];
    float acc = 0.f;
#pragma unroll
    for (int k = 0; k < MAX_DEG; ++k) {
        bool skip = (ids[k] == -1);
#pragma unroll
        for (int l = 0; l < k; ++l) skip = skip || (ids[l] == ids[k]);
        if (!skip) acc += x[(base + ids[k]) * N_FEAT + f];
    }
    agg[node * N_FEAT + f] = acc;
}

// ---------------------------------------------------------------------------
// K2: h = relu(agg_x @ W1)   [8192,128] @ [128,256] -> [8192,256]
// 8 rows per block; thread t owns output column t; rows staged in LDS.
// LDS reads are wave-uniform broadcasts (conflict-free).
// ---------------------------------------------------------------------------
__global__ __launch_bounds__(256) void k_gemm1_relu(const float* __restrict__ agg,
                                                    const float* __restrict__ W1,
                                                    float* __restrict__ h) {
    __shared__ float xs[8][N_FEAT];
    const int r0 = blockIdx.x * 8;
    const int t  = threadIdx.x;
#pragma unroll
    for (int i = 0; i < 4; ++i) {
        int idx = t + i * 256;                  // 0..1023
        xs[idx >> 7][idx & 127] = agg[r0 * N_FEAT + idx];
    }
    __syncthreads();
    float acc[8] = {0, 0, 0, 0, 0, 0, 0, 0};
    for (int k = 0; k < N_FEAT; ++k) {
        float w = W1[k * N_HID + t];
#pragma unroll
        for (int r = 0; r < 8; ++r) acc[r] += xs[r][k] * w;
    }
#pragma unroll
    for (int r = 0; r < 8; ++r)
        h[(r0 + r) * N_HID + t] = fmaxf(acc[r], 0.f);
}

// ---------------------------------------------------------------------------
// K3: t2 = h @ W2   [8192,256] @ [256,64] -> [8192,64]
// 16 rows per block; thread = (row-group rg = t>>6, col = t&63); rows in LDS.
// hs reads are wave-uniform broadcasts (one rg per wave).
// ---------------------------------------------------------------------------
__global__ __launch_bounds__(256) void k_gemm2(const float* __restrict__ h,
                                               const float* __restrict__ W2,
                                               float* __restrict__ t2) {
    __shared__ float hs[16][N_HID];
    const int r0 = blockIdx.x * 16;
    const int t  = threadIdx.x;
#pragma unroll
    for (int i = 0; i < 16; ++i)
        hs[i][t] = h[(r0 + i) * N_HID + t];
    __syncthreads();
    const int col = t & 63;
    const int rg  = t >> 6;                     // 0..3, uniform per wave
    float acc[4] = {0, 0, 0, 0};
    for (int k = 0; k < N_HID; ++k) {
        float w = W2[k * N_CLASS + col];
#pragma unroll
        for (int j = 0; j < 4; ++j) acc[j] += hs[rg * 4 + j][k] * w;
    }
#pragma unroll
    for (int j = 0; j < 4; ++j)
        t2[(r0 + rg * 4 + j) * N_CLASS + col] = acc[j];
}

// ---------------------------------------------------------------------------
// K4: out = log_softmax(adj @ t2)   one wave per node, lane = class
// ---------------------------------------------------------------------------
__global__ __launch_bounds__(256) void k_agg_lsm(const float* __restrict__ t2,
                                                 const int* __restrict__ edge,
                                                 float* __restrict__ out) {
    const int node = blockIdx.x * 4 + (threadIdx.x >> 6);
    const int lane = threadIdx.x & 63;
    const int base = node & ~(NODE_NUM - 1);
    const int* e = edge + node * MAX_DEG;
    int ids[MAX_DEG];
#pragma unroll
    for (int k = 0; k < MAX_DEG; ++k) ids[k] = e[k];
    float acc = 0.f;
#pragma unroll
    for (int k = 0; k < MAX_DEG; ++k) {
        bool skip = (ids[k] == -1);
#pragma unroll
        for (int l = 0; l < k; ++l) skip = skip || (ids[l] == ids[k]);
        if (!skip) acc += t2[(base + ids[k]) * N_CLASS + lane];
    }
    // log-softmax across the 64 lanes of the wave
    float m = acc;
#pragma unroll
    for (int o = 32; o > 0; o >>= 1) m = fmaxf(m, __shfl_xor(m, o, 64));
    float s = expf(acc - m);
#pragma unroll
    for (int o = 32; o > 0; o >>= 1) s += __shfl_xor(s, o, 64);
    out[node * N_CLASS + lane] = acc - m - logf(s);
}

// ---------------------------------------------------------------------------
extern "C" void kernel_launch(void* const* d_in, const int* in_sizes, int n_in,
                              void* d_out, int out_size, void* d_ws, size_t ws_size,
                              hipStream_t stream) {
    const float* x    = (const float*)d_in[0];
    const int*   edge = (const int*)d_in[1];
    const float* W1   = (const float*)d_in[2];
    const float* W2   = (const float*)d_in[3];
    float* out = (float*)d_out;

    char* ws = (char*)d_ws;
    float* agg = (float*)(ws);                                         // 4 MB
    float* h   = (float*)(ws + (size_t)NNODES * N_FEAT * 4);           // 8 MB
    float* t2  = (float*)(ws + (size_t)NNODES * (N_FEAT + N_HID) * 4); // 2 MB

    k_agg_x    <<<NNODES / 2,  256, 0, stream>>>(x, edge, agg);
    k_gemm1_relu<<<NNODES / 8, 256, 0, stream>>>(agg, W1, h);
    k_gemm2    <<<NNODES / 16, 256, 0, stream>>>(h, W2, t2);
    k_agg_lsm  <<<NNODES / 4,  256, 0, stream>>>(t2, edge, out);
}

// Round 2
// 101.004 us; speedup vs baseline: 1.1393x; 1.1393x over previous
//
#include <hip/hip_runtime.h>
#include <math.h>

#define NNODES   8192
#define NODE_NUM 256
#define MAX_DEG  16
#define N_FEAT   128
#define N_HID    256
#define N_CLASS  64

// ---------------------------------------------------------------------------
// K0: per-node dedup/validity bitmask (bit k set = edge k valid and not a dup
// of an earlier slot). Computed ONCE instead of per-thread in both agg loops.
// ---------------------------------------------------------------------------
__global__ __launch_bounds__(256) void k_mask(const int* __restrict__ edge,
                                              unsigned int* __restrict__ mask) {
    const int node = blockIdx.x * 256 + threadIdx.x;
    const int* e = edge + node * MAX_DEG;
    int ids[MAX_DEG];
#pragma unroll
    for (int k = 0; k < MAX_DEG; ++k) ids[k] = e[k];
    unsigned int m = 0;
#pragma unroll
    for (int k = 0; k < MAX_DEG; ++k) {
        bool skip = (ids[k] == -1);
#pragma unroll
        for (int l = 0; l < k; ++l) skip = skip || (ids[l] == ids[k]);
        if (!skip) m |= (1u << k);
    }
    mask[node] = m;
}

// ---------------------------------------------------------------------------
// KA: fused  t2 = (relu((A@x) @ W1)) @ W2   for 8 nodes per block.
//   phase 1: gather-aggregate 8 rows of x into LDS (32 threads/node, 4 f each)
//   phase 2: GEMM1+relu, thread t owns hidden col t, float4 LDS broadcasts
//   phase 3: GEMM2, thread -> (2 rows, class col)
// ---------------------------------------------------------------------------
__global__ __launch_bounds__(256) void k_fused(const float* __restrict__ x,
                                               const int* __restrict__ edge,
                                               const unsigned int* __restrict__ mask,
                                               const float* __restrict__ W1,
                                               const float* __restrict__ W2,
                                               float* __restrict__ t2) {
    __shared__ float xs[8][N_FEAT];   // 4 KB
    __shared__ float hs[8][N_HID];    // 8 KB
    const int t = threadIdx.x;

    // ---- phase 1: aggregate x rows ----
    {
        const int n    = t >> 5;          // local node 0..7
        const int f0   = t & 31;          // feature lane; covers f0+{0,32,64,96}
        const int node = blockIdx.x * 8 + n;
        const int base = node & ~(NODE_NUM - 1);
        const int* e = edge + node * MAX_DEG;
        const unsigned int m = mask[node];
        int ids[MAX_DEG];
#pragma unroll
        for (int k = 0; k < MAX_DEG; ++k) ids[k] = e[k];
        float a0 = 0.f, a1 = 0.f, a2 = 0.f, a3 = 0.f;
#pragma unroll
        for (int k = 0; k < MAX_DEG; ++k) {
            if (m & (1u << k)) {
                const float* row = x + (size_t)(base + ids[k]) * N_FEAT;
                a0 += row[f0];
                a1 += row[f0 + 32];
                a2 += row[f0 + 64];
                a3 += row[f0 + 96];
            }
        }
        xs[n][f0]      = a0;
        xs[n][f0 + 32] = a1;
        xs[n][f0 + 64] = a2;
        xs[n][f0 + 96] = a3;
    }
    __syncthreads();

    // ---- phase 2: h = relu(xs @ W1), thread t owns column t ----
    {
        float acc[8] = {0, 0, 0, 0, 0, 0, 0, 0};
        const float4* xs4 = (const float4*)&xs[0][0];   // [8][32]
        for (int k4 = 0; k4 < N_FEAT / 4; ++k4) {
            float w0 = W1[(k4 * 4 + 0) * N_HID + t];
            float w1 = W1[(k4 * 4 + 1) * N_HID + t];
            float w2 = W1[(k4 * 4 + 2) * N_HID + t];
            float w3 = W1[(k4 * 4 + 3) * N_HID + t];
#pragma unroll
            for (int r = 0; r < 8; ++r) {
                float4 xv = xs4[r * 32 + k4];           // ds_read_b128 broadcast
                acc[r] += xv.x * w0 + xv.y * w1 + xv.z * w2 + xv.w * w3;
            }
        }
        __syncthreads();   // xs reads done before hs overwrites nothing; order safety
#pragma unroll
        for (int r = 0; r < 8; ++r) hs[r][t] = fmaxf(acc[r], 0.f);
    }
    __syncthreads();

    // ---- phase 3: t2 = hs @ W2, thread -> (rows rg*2, rg*2+1; col) ----
    {
        const int col = t & 63;
        const int rg  = t >> 6;           // 0..3 (wave-uniform)
        const float4* hs4 = (const float4*)&hs[0][0];   // [8][64]
        float b0 = 0.f, b1 = 0.f;
        for (int k4 = 0; k4 < N_HID / 4; ++k4) {
            float w0 = W2[(k4 * 4 + 0) * N_CLASS + col];
            float w1 = W2[(k4 * 4 + 1) * N_CLASS + col];
            float w2 = W2[(k4 * 4 + 2) * N_CLASS + col];
            float w3 = W2[(k4 * 4 + 3) * N_CLASS + col];
            float4 h0 = hs4[(rg * 2 + 0) * 64 + k4];    // broadcast
            float4 h1 = hs4[(rg * 2 + 1) * 64 + k4];
            b0 += h0.x * w0 + h0.y * w1 + h0.z * w2 + h0.w * w3;
            b1 += h1.x * w0 + h1.y * w1 + h1.z * w2 + h1.w * w3;
        }
        const int r0 = blockIdx.x * 8 + rg * 2;
        t2[(size_t)r0 * N_CLASS + col]       = b0;
        t2[(size_t)(r0 + 1) * N_CLASS + col] = b1;
    }
}

// ---------------------------------------------------------------------------
// KB: out = log_softmax(A @ t2)   one wave per node, lane = class
// ---------------------------------------------------------------------------
__global__ __launch_bounds__(256) void k_agg_lsm(const float* __restrict__ t2,
                                                 const int* __restrict__ edge,
                                                 const unsigned int* __restrict__ mask,
                                                 float* __restrict__ out) {
    const int node = blockIdx.x * 4 + (threadIdx.x >> 6);
    const int lane = threadIdx.x & 63;
    const int base = node & ~(NODE_NUM - 1);
    const int* e = edge + node * MAX_DEG;
    const unsigned int m = mask[node];
    int ids[MAX_DEG];
#pragma unroll
    for (int k = 0; k < MAX_DEG; ++k) ids[k] = e[k];
    float acc = 0.f;
#pragma unroll
    for (int k = 0; k < MAX_DEG; ++k) {
        if (m & (1u << k)) acc += t2[(size_t)(base + ids[k]) * N_CLASS + lane];
    }
    float mx = acc;
#pragma unroll
    for (int o = 32; o > 0; o >>= 1) mx = fmaxf(mx, __shfl_xor(mx, o, 64));
    float s = expf(acc - mx);
#pragma unroll
    for (int o = 32; o > 0; o >>= 1) s += __shfl_xor(s, o, 64);
    out[node * N_CLASS + lane] = acc - mx - logf(s);
}

// ---------------------------------------------------------------------------
extern "C" void kernel_launch(void* const* d_in, const int* in_sizes, int n_in,
                              void* d_out, int out_size, void* d_ws, size_t ws_size,
                              hipStream_t stream) {
    const float* x    = (const float*)d_in[0];
    const int*   edge = (const int*)d_in[1];
    const float* W1   = (const float*)d_in[2];
    const float* W2   = (const float*)d_in[3];
    float* out = (float*)d_out;

    char* ws = (char*)d_ws;
    unsigned int* mask = (unsigned int*)ws;                    // 32 KB
    float*        t2   = (float*)(ws + 64 * 1024);             // 2 MB

    k_mask   <<<NNODES / 256, 256, 0, stream>>>(edge, mask);
    k_fused  <<<NNODES / 8,   256, 0, stream>>>(x, edge, mask, W1, W2, t2);
    k_agg_lsm<<<NNODES / 4,   256, 0, stream>>>(t2, edge, mask, out);
}

// Round 3
// 89.430 us; speedup vs baseline: 1.2868x; 1.1294x over previous
//
#include <hip/hip_runtime.h>
#include <math.h>

#define NNODES   8192
#define NODE_NUM 256
#define MAX_DEG  16
#define N_FEAT   128
#define N_HID    256
#define N_CLASS  64

typedef __attribute__((ext_vector_type(8))) short bf16x8;
typedef __attribute__((ext_vector_type(4))) float f32x4;

// f32 -> bf16 with round-to-nearest-even
static __device__ __forceinline__ short f2b(float f) {
    unsigned u = __float_as_uint(f);
    unsigned r = (u + 0x7fffu + ((u >> 16) & 1u)) >> 16;
    return (short)r;
}

// ---------------------------------------------------------------------------
// K0: prep — dedup mask per node; W1^T and W2^T converted to bf16.
// blocks [0,32): mask; [32,160): W1T [256][128]; [160,224): W2T [64][256]
// ---------------------------------------------------------------------------
__global__ __launch_bounds__(256) void k_prep(const int* __restrict__ edge,
                                              const float* __restrict__ W1,
                                              const float* __restrict__ W2,
                                              unsigned int* __restrict__ mask,
                                              short* __restrict__ W1T,
                                              short* __restrict__ W2T) {
    const int b = blockIdx.x, t = threadIdx.x;
    if (b < 32) {
        const int node = b * 256 + t;
        const int* e = edge + node * MAX_DEG;
        int ids[MAX_DEG];
#pragma unroll
        for (int k = 0; k < MAX_DEG; ++k) ids[k] = e[k];
        unsigned int m = 0;
#pragma unroll
        for (int k = 0; k < MAX_DEG; ++k) {
            bool skip = (ids[k] == -1);
#pragma unroll
            for (int l = 0; l < k; ++l) skip = skip || (ids[l] == ids[k]);
            if (!skip) m |= (1u << k);
        }
        mask[node] = m;
    } else if (b < 160) {
        const int i = (b - 32) * 256 + t;     // n*128 + k
        const int n = i >> 7, k = i & 127;
        W1T[i] = f2b(W1[k * N_HID + n]);
    } else {
        const int i = (b - 160) * 256 + t;    // n*256 + k
        const int n = i >> 8, k = i & 255;
        W2T[i] = f2b(W2[k * N_CLASS + n]);
    }
}

// ---------------------------------------------------------------------------
// K1: fused  t2 = relu((A@x)@W1) @ W2  for 32 rows per 512-thread block.
//   phase 1: gather-aggregate x rows (f32) -> bf16 LDS tile (padded stride)
//   phase 2: MFMA GEMM1 + relu -> h bf16 LDS
//   phase 3: MFMA GEMM2 -> t2 f32 global
// MFMA 16x16x32 bf16 layouts (m89/m92-verified):
//   A: lane l holds A[row=l&15][k=8*(l>>4)+j], j=0..7 (contiguous K -> b128)
//   B: lane l holds B[k=8*(l>>4)+j][col=l&15]  (B^T rows contiguous in K)
//   C: reg r -> row=(l>>4)*4+r, col=l&15
// ---------------------------------------------------------------------------
__global__ __launch_bounds__(512) void k_main(const float* __restrict__ x,
                                              const int* __restrict__ edge,
                                              const unsigned int* __restrict__ mask,
                                              const short* __restrict__ W1T,
                                              const short* __restrict__ W2T,
                                              float* __restrict__ t2) {
    __shared__ short agg[32 * 136];   // [32][128+8] bf16, row stride 272 B
    __shared__ short hb[32 * 264];    // [32][256+8] bf16, row stride 528 B

    const int t = threadIdx.x;
    const int row0 = blockIdx.x * 32;

    // ---- phase 1: aggregate neighbors' x rows (binary adj via mask) ----
    {
        const int r = t >> 4;                 // local row 0..31
        const int c = t & 15;                 // 8-float chunk
        const int node = row0 + r;
        const int base = node & ~(NODE_NUM - 1);
        const int* e = edge + node * MAX_DEG;
        const unsigned int m = mask[node];
        float a[8] = {0, 0, 0, 0, 0, 0, 0, 0};
#pragma unroll
        for (int k = 0; k < MAX_DEG; ++k) {
            if (m & (1u << k)) {
                const float* rowp = x + (size_t)(base + e[k]) * N_FEAT + c * 8;
                float4 v0 = *(const float4*)(rowp);
                float4 v1 = *(const float4*)(rowp + 4);
                a[0] += v0.x; a[1] += v0.y; a[2] += v0.z; a[3] += v0.w;
                a[4] += v1.x; a[5] += v1.y; a[6] += v1.z; a[7] += v1.w;
            }
        }
        bf16x8 p;
#pragma unroll
        for (int j = 0; j < 8; ++j) p[j] = f2b(a[j]);
        *(bf16x8*)(&agg[r * 136 + c * 8]) = p;
    }
    __syncthreads();

    const int w   = t >> 6;                   // wave 0..7
    const int l   = t & 63;
    const int l16 = l & 15, l4 = l >> 4;

    // ---- phase 2: h = relu(agg @ W1)  [32x128]x[128x256] ----
    {
        const int mt = w >> 2;                // M-tile 0..1
        bf16x8 afrag[4];
#pragma unroll
        for (int k4 = 0; k4 < 4; ++k4)
            afrag[k4] = *(const bf16x8*)(&agg[(mt * 16 + l16) * 136 + k4 * 32 + l4 * 8]);
#pragma unroll
        for (int n = 0; n < 4; ++n) {
            const int nt = (w & 3) * 4 + n;   // N-tile 0..15
            f32x4 acc = {0.f, 0.f, 0.f, 0.f};
#pragma unroll
            for (int k4 = 0; k4 < 4; ++k4) {
                bf16x8 b = *(const bf16x8*)(W1T + (nt * 16 + l16) * 128 + k4 * 32 + l4 * 8);
                acc = __builtin_amdgcn_mfma_f32_16x16x32_bf16(afrag[k4], b, acc, 0, 0, 0);
            }
#pragma unroll
            for (int r = 0; r < 4; ++r) {
                const int rr = mt * 16 + l4 * 4 + r;
                hb[rr * 264 + nt * 16 + l16] = f2b(fmaxf(acc[r], 0.f));
            }
        }
    }
    __syncthreads();

    // ---- phase 3: t2 = h @ W2  [32x256]x[256x64] ----
    {
        const int mt = w >> 2, nt = w & 3;    // 8 waves = 2M x 4N tiles
        f32x4 acc = {0.f, 0.f, 0.f, 0.f};
#pragma unroll
        for (int k8 = 0; k8 < 8; ++k8) {
            bf16x8 a = *(const bf16x8*)(&hb[(mt * 16 + l16) * 264 + k8 * 32 + l4 * 8]);
            bf16x8 b = *(const bf16x8*)(W2T + (nt * 16 + l16) * 256 + k8 * 32 + l4 * 8);
            acc = __builtin_amdgcn_mfma_f32_16x16x32_bf16(a, b, acc, 0, 0, 0);
        }
#pragma unroll
        for (int r = 0; r < 4; ++r)
            t2[(size_t)(row0 + mt * 16 + l4 * 4 + r) * N_CLASS + nt * 16 + l16] = acc[r];
    }
}

// ---------------------------------------------------------------------------
// K2: out = log_softmax(A @ t2)   one wave per node, lane = class
// ---------------------------------------------------------------------------
__global__ __launch_bounds__(256) void k_final(const float* __restrict__ t2,
                                               const int* __restrict__ edge,
                                               const unsigned int* __restrict__ mask,
                                               float* __restrict__ out) {
    const int node = blockIdx.x * 4 + (threadIdx.x >> 6);
    const int lane = threadIdx.x & 63;
    const int base = node & ~(NODE_NUM - 1);
    const int* e = edge + node * MAX_DEG;
    const unsigned int m = mask[node];
    int ids[MAX_DEG];
#pragma unroll
    for (int k = 0; k < MAX_DEG; ++k) ids[k] = e[k];
    float acc = 0.f;
#pragma unroll
    for (int k = 0; k < MAX_DEG; ++k) {
        if (m & (1u << k)) acc += t2[(size_t)(base + ids[k]) * N_CLASS + lane];
    }
    float mx = acc;
#pragma unroll
    for (int o = 32; o > 0; o >>= 1) mx = fmaxf(mx, __shfl_xor(mx, o, 64));
    float s = expf(acc - mx);
#pragma unroll
    for (int o = 32; o > 0; o >>= 1) s += __shfl_xor(s, o, 64);
    out[node * N_CLASS + lane] = acc - mx - logf(s);
}

// ---------------------------------------------------------------------------
extern "C" void kernel_launch(void* const* d_in, const int* in_sizes, int n_in,
                              void* d_out, int out_size, void* d_ws, size_t ws_size,
                              hipStream_t stream) {
    const float* x    = (const float*)d_in[0];
    const int*   edge = (const int*)d_in[1];
    const float* W1   = (const float*)d_in[2];
    const float* W2   = (const float*)d_in[3];
    float* out = (float*)d_out;

    char* ws = (char*)d_ws;
    unsigned int* mask = (unsigned int*)(ws);                  // 32 KB
    short*        W1T  = (short*)(ws + (32 << 10));            // 64 KB
    short*        W2T  = (short*)(ws + (96 << 10));            // 32 KB
    float*        t2   = (float*)(ws + (128 << 10));           // 2 MB

    k_prep <<<224,         256, 0, stream>>>(edge, W1, W2, mask, W1T, W2T);
    k_main <<<NNODES / 32, 512, 0, stream>>>(x, edge, mask, W1T, W2T, t2);
    k_final<<<NNODES / 4,  256, 0, stream>>>(t2, edge, mask, out);
}